// Round 1
// baseline (383.304 us; speedup 1.0000x reference)
//
#include <hip/hip_runtime.h>
#include <math.h>

#define NN    50000
#define DEG   16
#define FIN   256
#define FOUT  128
#define EE    (NN * DEG)
#define ALPHA 0.2f

// ---------------------------------------------------------------------------
// Phase A: h_hi = x @ W_high, h_lo = x @ W_low  (fp32, no MFMA on CDNA4)
// Tile: 64 rows x 256 cols (hi|lo side by side), K-step 32.
// 256 threads; each thread computes an 8x8 register tile.
// ---------------------------------------------------------------------------
__global__ __launch_bounds__(256) void gemm_h_kernel(
    const float* __restrict__ x,
    const float* __restrict__ Wh,
    const float* __restrict__ Wl,
    float* __restrict__ h_hi,
    float* __restrict__ h_lo)
{
    __shared__ float xs[64][33];   // +1 pad
    __shared__ float ws[32][256];  // cols 0..127 = W_high, 128..255 = W_low

    const int t  = threadIdx.x;
    const int tx = t & 31;   // col group: cols [tx*8, tx*8+8)
    const int ty = t >> 5;   // row group: rows ty + 8*rr
    const int r0 = blockIdx.x * 64;

    float acc[8][8];
#pragma unroll
    for (int i = 0; i < 8; ++i)
#pragma unroll
        for (int j = 0; j < 8; ++j) acc[i][j] = 0.f;

    const int xrow = t >> 2;        // 0..63
    const int xk   = (t & 3) * 8;   // 0,8,16,24
    const int grow = min(r0 + xrow, NN - 1);  // clamp tail rows (not stored)

    for (int k0 = 0; k0 < FIN; k0 += 32) {
        // issue global loads for x tile early
        const float4 xa = *(const float4*)&x[(size_t)grow * FIN + k0 + xk];
        const float4 xb = *(const float4*)&x[(size_t)grow * FIN + k0 + xk + 4];

        __syncthreads();  // previous iteration's reads done

        xs[xrow][xk + 0] = xa.x; xs[xrow][xk + 1] = xa.y;
        xs[xrow][xk + 2] = xa.z; xs[xrow][xk + 3] = xa.w;
        xs[xrow][xk + 4] = xb.x; xs[xrow][xk + 5] = xb.y;
        xs[xrow][xk + 6] = xb.z; xs[xrow][xk + 7] = xb.w;

        // stage W tile: thread t owns column t across 32 k-rows
#pragma unroll
        for (int j = 0; j < 32; ++j) {
            const float v = (t < 128)
                ? Wh[(size_t)(k0 + j) * FOUT + t]
                : Wl[(size_t)(k0 + j) * FOUT + (t - 128)];
            ws[j][t] = v;
        }

        __syncthreads();

#pragma unroll 8
        for (int k = 0; k < 32; ++k) {
            float a[8];
#pragma unroll
            for (int rr = 0; rr < 8; ++rr) a[rr] = xs[ty + rr * 8][k];
            const float4 b0 = *(const float4*)&ws[k][tx * 8];
            const float4 b1 = *(const float4*)&ws[k][tx * 8 + 4];
            const float b[8] = {b0.x, b0.y, b0.z, b0.w, b1.x, b1.y, b1.z, b1.w};
#pragma unroll
            for (int rr = 0; rr < 8; ++rr)
#pragma unroll
                for (int cc = 0; cc < 8; ++cc)
                    acc[rr][cc] += a[rr] * b[cc];
        }
    }

    // epilogue: tx<16 -> h_hi cols [tx*8..), tx>=16 -> h_lo cols [(tx-16)*8..)
#pragma unroll
    for (int rr = 0; rr < 8; ++rr) {
        const int row = r0 + ty + rr * 8;
        if (row >= NN) continue;
        float4 v0, v1;
        v0.x = acc[rr][0]; v0.y = acc[rr][1]; v0.z = acc[rr][2]; v0.w = acc[rr][3];
        v1.x = acc[rr][4]; v1.y = acc[rr][5]; v1.z = acc[rr][6]; v1.w = acc[rr][7];
        if (tx < 16) {
            *(float4*)&h_hi[(size_t)row * FOUT + tx * 8]     = v0;
            *(float4*)&h_hi[(size_t)row * FOUT + tx * 8 + 4] = v1;
        } else {
            *(float4*)&h_lo[(size_t)row * FOUT + (tx - 16) * 8]     = v0;
            *(float4*)&h_lo[(size_t)row * FOUT + (tx - 16) * 8 + 4] = v1;
        }
    }
}

// ---------------------------------------------------------------------------
// Phase B: hn_hi[i] = 16*h_hi[i] + sum_d h_hi[d]
//          hn_lo[i] = 16*h_lo[i] - sum_d h_lo[d]
//          + the four per-node logit scalars s_hi,d_hi,s_lo,d_lo = h[i].a
// One wave (64 lanes) per node; lane holds a float2 of the 128-wide row.
// ---------------------------------------------------------------------------
__global__ __launch_bounds__(256) void hn_kernel(
    const float* __restrict__ h_hi, const float* __restrict__ h_lo,
    const int* __restrict__ dst,
    const float* __restrict__ a_high, const float* __restrict__ a_low,
    float* __restrict__ hn_hi, float* __restrict__ hn_lo,
    float* __restrict__ sd)   // sd: [4][NN]  (s_hi, d_hi, s_lo, d_lo)
{
    const int wid  = (blockIdx.x * 256 + threadIdx.x) >> 6;
    const int lane = threadIdx.x & 63;
    if (wid >= NN) return;

    const float2 own_hi = ((const float2*)(h_hi + (size_t)wid * FOUT))[lane];
    const float2 own_lo = ((const float2*)(h_lo + (size_t)wid * FOUT))[lane];

    float2 acc_hi = make_float2(16.f * own_hi.x, 16.f * own_hi.y);
    float2 acc_lo = make_float2(16.f * own_lo.x, 16.f * own_lo.y);

    const int* de = dst + (size_t)wid * DEG;
#pragma unroll
    for (int e = 0; e < DEG; ++e) {
        const int d = de[e];
        const float2 g_hi = ((const float2*)(h_hi + (size_t)d * FOUT))[lane];
        const float2 g_lo = ((const float2*)(h_lo + (size_t)d * FOUT))[lane];
        acc_hi.x += g_hi.x; acc_hi.y += g_hi.y;
        acc_lo.x -= g_lo.x; acc_lo.y -= g_lo.y;
    }
    ((float2*)(hn_hi + (size_t)wid * FOUT))[lane] = acc_hi;
    ((float2*)(hn_lo + (size_t)wid * FOUT))[lane] = acc_lo;

    // logit dot products (fp32 path — precision-critical, see round-0 analysis)
    const float2 as_hi = ((const float2*)a_high)[lane];
    const float2 ad_hi = ((const float2*)a_high)[64 + lane];
    const float2 as_lo = ((const float2*)a_low)[lane];
    const float2 ad_lo = ((const float2*)a_low)[64 + lane];
    float p0 = own_hi.x * as_hi.x + own_hi.y * as_hi.y;
    float p1 = own_hi.x * ad_hi.x + own_hi.y * ad_hi.y;
    float p2 = own_lo.x * as_lo.x + own_lo.y * as_lo.y;
    float p3 = own_lo.x * ad_lo.x + own_lo.y * ad_lo.y;
#pragma unroll
    for (int off = 32; off > 0; off >>= 1) {
        p0 += __shfl_xor(p0, off);
        p1 += __shfl_xor(p1, off);
        p2 += __shfl_xor(p2, off);
        p3 += __shfl_xor(p3, off);
    }
    if (lane == 0) {
        sd[0 * NN + wid] = p0;
        sd[1 * NN + wid] = p1;
        sd[2 * NN + wid] = p2;
        sd[3 * NN + wid] = p3;
    }
}

// ---------------------------------------------------------------------------
// Phase C: per-edge attention weights + weighted gather of hn[dst] + elu6.
// rowsum uses UNCLIPPED e; numerator uses clip(e,0,6) — matches reference.
// One wave per node.
// ---------------------------------------------------------------------------
__global__ __launch_bounds__(256) void out_kernel(
    const float* __restrict__ hn_hi, const float* __restrict__ hn_lo,
    const int* __restrict__ dst, const float* __restrict__ sd,
    float* __restrict__ out)
{
    const int wid  = (blockIdx.x * 256 + threadIdx.x) >> 6;
    const int lane = threadIdx.x & 63;
    if (wid >= NN) return;

    const float s_hi = sd[0 * NN + wid];
    const float s_lo = sd[2 * NN + wid];

    float2 acc_hi = make_float2(0.f, 0.f);
    float2 acc_lo = make_float2(0.f, 0.f);
    float rs_hi = 0.f, rs_lo = 0.f;

    const int* de = dst + (size_t)wid * DEG;
#pragma unroll
    for (int e = 0; e < DEG; ++e) {
        const int d = de[e];
        const float l_hi = s_hi + sd[1 * NN + d];
        const float l_lo = s_lo + sd[3 * NN + d];
        const float e_hi = expf(-(l_hi >= 0.f ? l_hi : ALPHA * l_hi));
        const float e_lo = expf(-(l_lo >= 0.f ? l_lo : ALPHA * l_lo));
        rs_hi += e_hi; rs_lo += e_lo;
        const float w_hi = fminf(e_hi, 6.f);
        const float w_lo = fminf(e_lo, 6.f);
        const float2 g_hi = ((const float2*)(hn_hi + (size_t)d * FOUT))[lane];
        const float2 g_lo = ((const float2*)(hn_lo + (size_t)d * FOUT))[lane];
        acc_hi.x += w_hi * g_hi.x; acc_hi.y += w_hi * g_hi.y;
        acc_lo.x += w_lo * g_lo.x; acc_lo.y += w_lo * g_lo.y;
    }

    const float inv_hi = 1.f / (rs_hi + 1e-16f);
    const float inv_lo = 1.f / (rs_lo + 1e-16f);
    float vx = 0.5f * (acc_hi.x * inv_hi + acc_lo.x * inv_lo);
    float vy = 0.5f * (acc_hi.y * inv_hi + acc_lo.y * inv_lo);
    vx = fminf(vx > 0.f ? vx : expm1f(vx), 6.f);
    vy = fminf(vy > 0.f ? vy : expm1f(vy), 6.f);
    ((float2*)(out + (size_t)wid * FOUT))[lane] = make_float2(vx, vy);
}

// ---------------------------------------------------------------------------
extern "C" void kernel_launch(void* const* d_in, const int* in_sizes, int n_in,
                              void* d_out, int out_size, void* d_ws, size_t ws_size,
                              hipStream_t stream)
{
    const float* x      = (const float*)d_in[0];
    const int*   edge   = (const int*)d_in[1];
    const float* Wh     = (const float*)d_in[2];
    const float* Wl     = (const float*)d_in[3];
    const float* a_high = (const float*)d_in[4];
    const float* a_low  = (const float*)d_in[5];
    const int*   dstv   = edge + EE;   // edge[0]=src (= repeat(arange(N),16)), edge[1]=dst

    float* wsf   = (float*)d_ws;       // need ~103.2 MB of workspace
    float* h_hi  = wsf;
    float* h_lo  = h_hi  + (size_t)NN * FOUT;
    float* hn_hi = h_lo  + (size_t)NN * FOUT;
    float* hn_lo = hn_hi + (size_t)NN * FOUT;
    float* sd    = hn_lo + (size_t)NN * FOUT;   // 4*NN floats

    const dim3 blk(256);
    gemm_h_kernel<<<dim3((NN + 63) / 64), blk, 0, stream>>>(x, Wh, Wl, h_hi, h_lo);
    hn_kernel<<<dim3((NN + 3) / 4), blk, 0, stream>>>(h_hi, h_lo, dstv, a_high, a_low,
                                                      hn_hi, hn_lo, sd);
    out_kernel<<<dim3((NN + 3) / 4), blk, 0, stream>>>(hn_hi, hn_lo, dstv, sd,
                                                       (float*)d_out);
}

// Round 2
// 298.228 us; speedup vs baseline: 1.2853x; 1.2853x over previous
//
#include <hip/hip_runtime.h>
#include <hip/hip_bf16.h>
#include <math.h>

#define NN    50000
#define DEG   16
#define FIN   256
#define FOUT  128
#define EE    (NN * DEG)
#define ALPHA 0.2f

#define BM 64
#define BN 256
#define BK 32
#define KV 768   // virtual K: [xh|xl|xh] x [Wa;Wa;Wb]

typedef __hip_bfloat16 bf16;
typedef __attribute__((ext_vector_type(8))) short short8;
typedef __attribute__((ext_vector_type(4))) float f32x4;

// ---------------------------------------------------------------------------
// Split x (fp32 [NN][256]) into xcat (bf16 [NN][512] = [xh | xl]).
// bf16x3 trick: x = xh + xl to ~16 mantissa bits.
// ---------------------------------------------------------------------------
__global__ __launch_bounds__(256) void split_x_kernel(
    const float* __restrict__ x, bf16* __restrict__ xcat)
{
    const int total = NN * FIN / 4;   // float4 count
    for (int idx = blockIdx.x * 256 + threadIdx.x; idx < total; idx += gridDim.x * 256) {
        const float4 v = ((const float4*)x)[idx];
        const int row = idx >> 6;         // 64 float4 per 256-col row
        const int c4  = (idx & 63) * 4;
        short4 sh, sl;
        const float f[4] = {v.x, v.y, v.z, v.w};
#pragma unroll
        for (int j = 0; j < 4; ++j) {
            const bf16 hi = __float2bfloat16(f[j]);
            const bf16 lo = __float2bfloat16(f[j] - __bfloat162float(hi));
            ((bf16*)&sh)[j] = hi;
            ((bf16*)&sl)[j] = lo;
        }
        *(short4*)&xcat[(size_t)row * 512 + c4]       = sh;
        *(short4*)&xcat[(size_t)row * 512 + 256 + c4] = sl;
    }
}

// ---------------------------------------------------------------------------
// Build WcatT bf16 [256][768]: n-major, virtual-K columns [Wa | Wa | Wb],
// where W[k][n] = (n<128 ? W_high[k][n] : W_low[k][n-128]), Wa=hi, Wb=lo split.
// ---------------------------------------------------------------------------
__global__ __launch_bounds__(256) void split_w_kernel(
    const float* __restrict__ Wh, const float* __restrict__ Wl,
    bf16* __restrict__ WcatT)
{
    const int k = blockIdx.x;    // 0..255
    const int n = threadIdx.x;   // 0..255
    const float w = (n < FOUT) ? Wh[(size_t)k * FOUT + n]
                               : Wl[(size_t)k * FOUT + (n - FOUT)];
    const bf16 hi = __float2bfloat16(w);
    const bf16 lo = __float2bfloat16(w - __bfloat162float(hi));
    WcatT[(size_t)n * KV + k]       = hi;
    WcatT[(size_t)n * KV + 256 + k] = hi;
    WcatT[(size_t)n * KV + 512 + k] = lo;
}

// ---------------------------------------------------------------------------
// MFMA GEMM: h[50000][256] = A'(50000x768) @ B'(768x256), bf16 in, fp32 out.
// BM=64 x BN=256 block, 4 waves (each owns 64 N-cols), BK=32, 24 K-steps.
// LDS tiles [rows][32] bf16 (64B rows); slot-swizzle: phys_slot =
// (log_slot + (row>>1)) & 3 applied on BOTH the global source (staging via
// global_load_lds, linear dest) and the ds_read_b128 address (rule #21).
// ---------------------------------------------------------------------------
__global__ __launch_bounds__(256) void gemm_mfma_kernel(
    const bf16* __restrict__ xcat, const bf16* __restrict__ WcatT,
    float* __restrict__ h)
{
    __shared__ bf16 As[BM * BK];   //  4096 B
    __shared__ bf16 Bs[BN * BK];   // 16384 B

    const int t    = threadIdx.x;
    const int lane = t & 63;
    const int w    = t >> 6;
    const int r0   = blockIdx.x * BM;

    f32x4 acc[4][4] = {};   // [mi][ni]

    // A staging source: thread t covers LDS bytes [t*16, t*16+16)
    const int arow = t >> 2;
    const int asl  = ((t & 3) - (arow >> 1)) & 3;
    const size_t abase = (size_t)min(r0 + arow, NN - 1) * 512 + asl * 8;

    // B staging: 4 chunks per thread
    int bro[4], bsl[4];
#pragma unroll
    for (int i = 0; i < 4; ++i) {
        const int idx = t + i * 256;
        bro[i] = idx >> 2;
        bsl[i] = ((idx & 3) - (bro[i] >> 1)) & 3;
    }

    const int lr = lane & 15, lg = lane >> 4;

    for (int s = 0; s < KV / BK; ++s) {
        const int kt = s * BK;
        const int kA = (kt < 512) ? kt : kt - 512;

        __builtin_amdgcn_global_load_lds(
            (const __attribute__((address_space(1))) void*)(xcat + abase + kA),
            (__attribute__((address_space(3))) void*)((char*)As + t * 16),
            16, 0, 0);
#pragma unroll
        for (int i = 0; i < 4; ++i) {
            __builtin_amdgcn_global_load_lds(
                (const __attribute__((address_space(1))) void*)
                    (WcatT + (size_t)bro[i] * KV + kt + bsl[i] * 8),
                (__attribute__((address_space(3))) void*)((char*)Bs + (t + i * 256) * 16),
                16, 0, 0);
        }

        __syncthreads();   // vmcnt drain + barrier: tiles ready

        short8 af[4], bfr[4];
#pragma unroll
        for (int mi = 0; mi < 4; ++mi) {
            const int row  = mi * 16 + lr;
            const int slot = (lg + (row >> 1)) & 3;
            af[mi] = *(const short8*)((const char*)As + row * 64 + slot * 16);
        }
#pragma unroll
        for (int ni = 0; ni < 4; ++ni) {
            const int row  = w * 64 + ni * 16 + lr;
            const int slot = (lg + (row >> 1)) & 3;
            bfr[ni] = *(const short8*)((const char*)Bs + row * 64 + slot * 16);
        }
#pragma unroll
        for (int mi = 0; mi < 4; ++mi)
#pragma unroll
            for (int ni = 0; ni < 4; ++ni)
                acc[mi][ni] = __builtin_amdgcn_mfma_f32_16x16x32_bf16(
                    af[mi], bfr[ni], acc[mi][ni], 0, 0, 0);

        __syncthreads();   // protect tiles from next-step overwrite
    }

    // C write: col = w*64 + ni*16 + (lane&15); row = mi*16 + (lane>>4)*4 + r
#pragma unroll
    for (int mi = 0; mi < 4; ++mi) {
        const int rowb = r0 + mi * 16 + lg * 4;
#pragma unroll
        for (int r = 0; r < 4; ++r) {
            const int row = rowb + r;
            if (row >= NN) continue;
#pragma unroll
            for (int ni = 0; ni < 4; ++ni)
                h[(size_t)row * 256 + w * 64 + ni * 16 + lr] = acc[mi][ni][r];
        }
    }
}

// ---------------------------------------------------------------------------
// Phase B: hn[i] = [16*h_hi[i] + sum_d h_hi[d] | 16*h_lo[i] - sum_d h_lo[d]]
// + four per-node logit scalars sd = h[i].a  (fp32, precision-critical).
// h, hn are [NN][256] (cols 0..127 = hi, 128..255 = lo). One wave per node.
// ---------------------------------------------------------------------------
__global__ __launch_bounds__(256) void hn_kernel(
    const float* __restrict__ h, const int* __restrict__ dst,
    const float* __restrict__ a_high, const float* __restrict__ a_low,
    float* __restrict__ hn, float* __restrict__ sd)
{
    const int wid  = (blockIdx.x * 256 + threadIdx.x) >> 6;
    const int lane = threadIdx.x & 63;
    if (wid >= NN) return;

    const float* hrow = h + (size_t)wid * 256;
    const float2 own_hi = ((const float2*)hrow)[lane];
    const float2 own_lo = ((const float2*)(hrow + 128))[lane];

    float2 acc_hi = make_float2(16.f * own_hi.x, 16.f * own_hi.y);
    float2 acc_lo = make_float2(16.f * own_lo.x, 16.f * own_lo.y);

    const int* de = dst + (size_t)wid * DEG;
#pragma unroll
    for (int e = 0; e < DEG; ++e) {
        const float* hd = h + (size_t)de[e] * 256;
        const float2 g_hi = ((const float2*)hd)[lane];
        const float2 g_lo = ((const float2*)(hd + 128))[lane];
        acc_hi.x += g_hi.x; acc_hi.y += g_hi.y;
        acc_lo.x -= g_lo.x; acc_lo.y -= g_lo.y;
    }
    float* hnrow = hn + (size_t)wid * 256;
    ((float2*)hnrow)[lane]         = acc_hi;
    ((float2*)(hnrow + 128))[lane] = acc_lo;

    const float2 as_hi = ((const float2*)a_high)[lane];
    const float2 ad_hi = ((const float2*)a_high)[64 + lane];
    const float2 as_lo = ((const float2*)a_low)[lane];
    const float2 ad_lo = ((const float2*)a_low)[64 + lane];
    float p0 = own_hi.x * as_hi.x + own_hi.y * as_hi.y;
    float p1 = own_hi.x * ad_hi.x + own_hi.y * ad_hi.y;
    float p2 = own_lo.x * as_lo.x + own_lo.y * as_lo.y;
    float p3 = own_lo.x * ad_lo.x + own_lo.y * ad_lo.y;
#pragma unroll
    for (int off = 32; off > 0; off >>= 1) {
        p0 += __shfl_xor(p0, off);
        p1 += __shfl_xor(p1, off);
        p2 += __shfl_xor(p2, off);
        p3 += __shfl_xor(p3, off);
    }
    if (lane == 0) {
        sd[0 * NN + wid] = p0;
        sd[1 * NN + wid] = p1;
        sd[2 * NN + wid] = p2;
        sd[3 * NN + wid] = p3;
    }
}

// ---------------------------------------------------------------------------
// Phase C: per-edge weights + weighted gather of hn[dst] + elu6.
// rowsum uses UNCLIPPED e; numerator uses clip(e,0,6) — matches reference.
// ---------------------------------------------------------------------------
__global__ __launch_bounds__(256) void out_kernel(
    const float* __restrict__ hn, const int* __restrict__ dst,
    const float* __restrict__ sd, float* __restrict__ out)
{
    const int wid  = (blockIdx.x * 256 + threadIdx.x) >> 6;
    const int lane = threadIdx.x & 63;
    if (wid >= NN) return;

    const float s_hi = sd[0 * NN + wid];
    const float s_lo = sd[2 * NN + wid];

    float2 acc_hi = make_float2(0.f, 0.f);
    float2 acc_lo = make_float2(0.f, 0.f);
    float rs_hi = 0.f, rs_lo = 0.f;

    const int* de = dst + (size_t)wid * DEG;
#pragma unroll
    for (int e = 0; e < DEG; ++e) {
        const int d = de[e];
        const float l_hi = s_hi + sd[1 * NN + d];
        const float l_lo = s_lo + sd[3 * NN + d];
        const float e_hi = expf(-(l_hi >= 0.f ? l_hi : ALPHA * l_hi));
        const float e_lo = expf(-(l_lo >= 0.f ? l_lo : ALPHA * l_lo));
        rs_hi += e_hi; rs_lo += e_lo;
        const float w_hi = fminf(e_hi, 6.f);
        const float w_lo = fminf(e_lo, 6.f);
        const float* hd = hn + (size_t)d * 256;
        const float2 g_hi = ((const float2*)hd)[lane];
        const float2 g_lo = ((const float2*)(hd + 128))[lane];
        acc_hi.x += w_hi * g_hi.x; acc_hi.y += w_hi * g_hi.y;
        acc_lo.x += w_lo * g_lo.x; acc_lo.y += w_lo * g_lo.y;
    }

    const float inv_hi = 1.f / (rs_hi + 1e-16f);
    const float inv_lo = 1.f / (rs_lo + 1e-16f);
    float vx = 0.5f * (acc_hi.x * inv_hi + acc_lo.x * inv_lo);
    float vy = 0.5f * (acc_hi.y * inv_hi + acc_lo.y * inv_lo);
    vx = fminf(vx > 0.f ? vx : expm1f(vx), 6.f);
    vy = fminf(vy > 0.f ? vy : expm1f(vy), 6.f);
    ((float2*)(out + (size_t)wid * FOUT))[lane] = make_float2(vx, vy);
}

// ---------------------------------------------------------------------------
// Workspace layout (103.2 MB, same footprint as round 1, with aliasing):
//   [0, 51.2MB)      xcat bf16 [NN][512]   -- dead after GEMM, overlaid by
//                    hn  fp32 [NN][256]    (written by hn_kernel)
//   [51.2, 102.4MB)  h    fp32 [NN][256]
//   [102.4, 103.2MB) WcatT bf16 [256][768] -- dead after GEMM, overlaid by
//                    sd   fp32 [4][NN]     (written by hn_kernel)
// ---------------------------------------------------------------------------
extern "C" void kernel_launch(void* const* d_in, const int* in_sizes, int n_in,
                              void* d_out, int out_size, void* d_ws, size_t ws_size,
                              hipStream_t stream)
{
    const float* x      = (const float*)d_in[0];
    const int*   edge   = (const int*)d_in[1];
    const float* Wh     = (const float*)d_in[2];
    const float* Wl     = (const float*)d_in[3];
    const float* a_high = (const float*)d_in[4];
    const float* a_low  = (const float*)d_in[5];
    const int*   dstv   = edge + EE;   // edge[0]=src (= repeat(arange(N),16))

    char* ws = (char*)d_ws;
    bf16*  xcat  = (bf16*)ws;                          // 51,200,000 B
    float* hn    = (float*)ws;                         // alias (after GEMM)
    float* h     = (float*)(ws + 51200000);            // 51,200,000 B
    bf16*  WcatT = (bf16*)(ws + 102400000);            // 393,216 B
    float* sd    = (float*)(ws + 102400000);           // alias, 800,000 B

    split_x_kernel<<<dim3(2048), dim3(256), 0, stream>>>(x, xcat);
    split_w_kernel<<<dim3(256), dim3(256), 0, stream>>>(Wh, Wl, WcatT);
    gemm_mfma_kernel<<<dim3((NN + BM - 1) / BM), dim3(256), 0, stream>>>(xcat, WcatT, h);
    hn_kernel<<<dim3((NN + 3) / 4), dim3(256), 0, stream>>>(h, dstv, a_high, a_low, hn, sd);
    out_kernel<<<dim3((NN + 3) / 4), dim3(256), 0, stream>>>(hn, dstv, sd, (float*)d_out);
}

// Round 3
// 195.053 us; speedup vs baseline: 1.9651x; 1.5290x over previous
//
#include <hip/hip_runtime.h>
#include <hip/hip_bf16.h>
#include <math.h>

#define NN    50000
#define DEG   16
#define FIN   256
#define FOUT  128
#define EE    (NN * DEG)
#define ALPHA 0.2f

#define BM 64
#define BN 256
#define BK 32
#define KV 768   // virtual K: [xh|xl|xh] x [Wa;Wa;Wb]

typedef __hip_bfloat16 bf16;
typedef _Float16 f16;
typedef __attribute__((ext_vector_type(4))) _Float16 f16x4;
typedef __attribute__((ext_vector_type(8))) short short8;
typedef __attribute__((ext_vector_type(4))) float f32x4;

// ---------------------------------------------------------------------------
// Split x (fp32 [NN][256]) into xcat (bf16 [NN][512] = [xh | xl]).
// ---------------------------------------------------------------------------
__global__ __launch_bounds__(256) void split_x_kernel(
    const float* __restrict__ x, bf16* __restrict__ xcat)
{
    const int total = NN * FIN / 4;
    for (int idx = blockIdx.x * 256 + threadIdx.x; idx < total; idx += gridDim.x * 256) {
        const float4 v = ((const float4*)x)[idx];
        const int row = idx >> 6;
        const int c4  = (idx & 63) * 4;
        short4 sh, sl;
        const float f[4] = {v.x, v.y, v.z, v.w};
#pragma unroll
        for (int j = 0; j < 4; ++j) {
            const bf16 hi = __float2bfloat16(f[j]);
            const bf16 lo = __float2bfloat16(f[j] - __bfloat162float(hi));
            ((bf16*)&sh)[j] = hi;
            ((bf16*)&sl)[j] = lo;
        }
        *(short4*)&xcat[(size_t)row * 512 + c4]       = sh;
        *(short4*)&xcat[(size_t)row * 512 + 256 + c4] = sl;
    }
}

// ---------------------------------------------------------------------------
// Build WcatT bf16 [256][768]: [Wa | Wa | Wb] per n-row.
// ---------------------------------------------------------------------------
__global__ __launch_bounds__(256) void split_w_kernel(
    const float* __restrict__ Wh, const float* __restrict__ Wl,
    bf16* __restrict__ WcatT)
{
    const int k = blockIdx.x;
    const int n = threadIdx.x;
    const float w = (n < FOUT) ? Wh[(size_t)k * FOUT + n]
                               : Wl[(size_t)k * FOUT + (n - FOUT)];
    const bf16 hi = __float2bfloat16(w);
    const bf16 lo = __float2bfloat16(w - __bfloat162float(hi));
    WcatT[(size_t)n * KV + k]       = hi;
    WcatT[(size_t)n * KV + 256 + k] = hi;
    WcatT[(size_t)n * KV + 512 + k] = lo;
}

// ---------------------------------------------------------------------------
// MFMA GEMM: h16[50000][256] = A'(50000x768) @ B'(768x256), fp16 output.
// Same structure as round 2 (passed); only the epilogue dtype changed.
// ---------------------------------------------------------------------------
__global__ __launch_bounds__(256) void gemm_mfma_kernel(
    const bf16* __restrict__ xcat, const bf16* __restrict__ WcatT,
    f16* __restrict__ h16)
{
    __shared__ bf16 As[BM * BK];
    __shared__ bf16 Bs[BN * BK];

    const int t    = threadIdx.x;
    const int lane = t & 63;
    const int w    = t >> 6;
    const int r0   = blockIdx.x * BM;

    f32x4 acc[4][4] = {};

    const int arow = t >> 2;
    const int asl  = ((t & 3) - (arow >> 1)) & 3;
    const size_t abase = (size_t)min(r0 + arow, NN - 1) * 512 + asl * 8;

    int bro[4], bsl[4];
#pragma unroll
    for (int i = 0; i < 4; ++i) {
        const int idx = t + i * 256;
        bro[i] = idx >> 2;
        bsl[i] = ((idx & 3) - (bro[i] >> 1)) & 3;
    }

    const int lr = lane & 15, lg = lane >> 4;

    for (int s = 0; s < KV / BK; ++s) {
        const int kt = s * BK;
        const int kA = (kt < 512) ? kt : kt - 512;

        __builtin_amdgcn_global_load_lds(
            (const __attribute__((address_space(1))) void*)(xcat + abase + kA),
            (__attribute__((address_space(3))) void*)((char*)As + t * 16),
            16, 0, 0);
#pragma unroll
        for (int i = 0; i < 4; ++i) {
            __builtin_amdgcn_global_load_lds(
                (const __attribute__((address_space(1))) void*)
                    (WcatT + (size_t)bro[i] * KV + kt + bsl[i] * 8),
                (__attribute__((address_space(3))) void*)((char*)Bs + (t + i * 256) * 16),
                16, 0, 0);
        }

        __syncthreads();

        short8 af[4], bfr[4];
#pragma unroll
        for (int mi = 0; mi < 4; ++mi) {
            const int row  = mi * 16 + lr;
            const int slot = (lg + (row >> 1)) & 3;
            af[mi] = *(const short8*)((const char*)As + row * 64 + slot * 16);
        }
#pragma unroll
        for (int ni = 0; ni < 4; ++ni) {
            const int row  = w * 64 + ni * 16 + lr;
            const int slot = (lg + (row >> 1)) & 3;
            bfr[ni] = *(const short8*)((const char*)Bs + row * 64 + slot * 16);
        }
#pragma unroll
        for (int mi = 0; mi < 4; ++mi)
#pragma unroll
            for (int ni = 0; ni < 4; ++ni)
                acc[mi][ni] = __builtin_amdgcn_mfma_f32_16x16x32_bf16(
                    af[mi], bfr[ni], acc[mi][ni], 0, 0, 0);

        __syncthreads();
    }

#pragma unroll
    for (int mi = 0; mi < 4; ++mi) {
        const int rowb = r0 + mi * 16 + lg * 4;
#pragma unroll
        for (int r = 0; r < 4; ++r) {
            const int row = rowb + r;
            if (row >= NN) continue;
#pragma unroll
            for (int ni = 0; ni < 4; ++ni)
                h16[(size_t)row * 256 + w * 64 + ni * 16 + lr] = (f16)acc[mi][ni][r];
        }
    }
}

// ---------------------------------------------------------------------------
// Phase B: hn[i] = [16*h_hi[i] + sum_d h_hi[d] | 16*h_lo[i] - sum_d h_lo[d]]
// (fp16 gather table) + per-node logit scalars.
// One wave per node; lane L holds cols [4L, 4L+4): L<32 = hi, L>=32 = lo.
// ---------------------------------------------------------------------------
__global__ __launch_bounds__(256) void hn_kernel(
    const f16* __restrict__ h16, const int* __restrict__ dst,
    const float* __restrict__ a_high, const float* __restrict__ a_low,
    f16* __restrict__ hn16, float* __restrict__ sd_s, float* __restrict__ sd_d)
{
    const int wid  = (blockIdx.x * 256 + threadIdx.x) >> 6;
    const int lane = threadIdx.x & 63;
    if (wid >= NN) return;

    const f16x4 own4 = ((const f16x4*)(h16 + (size_t)wid * 256))[lane];
    float own[4], acc[4];
#pragma unroll
    for (int j = 0; j < 4; ++j) { own[j] = (float)own4[j]; acc[j] = 16.f * own[j]; }

    const float sgn = (lane < 32) ? 1.f : -1.f;
    const int* de = dst + (size_t)wid * DEG;
#pragma unroll
    for (int e = 0; e < DEG; ++e) {
        const f16x4 g = ((const f16x4*)(h16 + (size_t)de[e] * 256))[lane];
#pragma unroll
        for (int j = 0; j < 4; ++j) acc[j] += sgn * (float)g[j];
    }
    f16x4 o;
#pragma unroll
    for (int j = 0; j < 4; ++j) o[j] = (f16)acc[j];
    ((f16x4*)(hn16 + (size_t)wid * 256))[lane] = o;

    // logit scalars: lanes<32 -> (s_hi,d_hi) with a_high; lanes>=32 -> a_low
    const float* av = (lane < 32) ? a_high : a_low;
    const int c0 = (lane & 31) * 4;
    const float4 a_s = *(const float4*)(av + c0);
    const float4 a_d = *(const float4*)(av + 128 + c0);
    float ps = own[0] * a_s.x + own[1] * a_s.y + own[2] * a_s.z + own[3] * a_s.w;
    float pd = own[0] * a_d.x + own[1] * a_d.y + own[2] * a_d.z + own[3] * a_d.w;
#pragma unroll
    for (int off = 16; off > 0; off >>= 1) {
        ps += __shfl_xor(ps, off);
        pd += __shfl_xor(pd, off);
    }
    if ((lane & 31) == 0) {
        sd_s[wid * 2 + (lane >> 5)] = ps;   // [0]=s_hi, [1]=s_lo
        sd_d[wid * 2 + (lane >> 5)] = pd;   // [0]=d_hi, [1]=d_lo
    }
}

// ---------------------------------------------------------------------------
// Phase C: per-edge weights + weighted gather of hn16[dst] + hi/lo mix + elu6.
// rowsum uses UNCLIPPED e; numerator uses min(e,6) — matches reference.
// ---------------------------------------------------------------------------
__global__ __launch_bounds__(256) void out_kernel(
    const f16* __restrict__ hn16, const int* __restrict__ dst,
    const float* __restrict__ sd_s, const float* __restrict__ sd_d,
    float* __restrict__ out)
{
    const int wid  = (blockIdx.x * 256 + threadIdx.x) >> 6;
    const int lane = threadIdx.x & 63;
    if (wid >= NN) return;

    const float2 s2 = ((const float2*)sd_s)[wid];   // (s_hi, s_lo)
    const bool hi = (lane < 32);

    float acc[4] = {0.f, 0.f, 0.f, 0.f};
    float rs_hi = 0.f, rs_lo = 0.f;

    const int* de = dst + (size_t)wid * DEG;
#pragma unroll
    for (int e = 0; e < DEG; ++e) {
        const int d = de[e];
        const float2 dd = ((const float2*)sd_d)[d];
        const float l_hi = s2.x + dd.x;
        const float l_lo = s2.y + dd.y;
        const float e_hi = expf(-(l_hi >= 0.f ? l_hi : ALPHA * l_hi));
        const float e_lo = expf(-(l_lo >= 0.f ? l_lo : ALPHA * l_lo));
        rs_hi += e_hi; rs_lo += e_lo;
        const float w = hi ? fminf(e_hi, 6.f) : fminf(e_lo, 6.f);
        const f16x4 g = ((const f16x4*)(hn16 + (size_t)d * 256))[lane];
#pragma unroll
        for (int j = 0; j < 4; ++j) acc[j] += w * (float)g[j];
    }

    const float inv = hi ? 1.f / (rs_hi + 1e-16f) : 1.f / (rs_lo + 1e-16f);
    float4 v4;
#pragma unroll
    for (int j = 0; j < 4; ++j) {
        const float val = acc[j] * inv;
        const float other = __shfl_xor(val, 32);
        float v = 0.5f * (val + other);
        v = fminf(v > 0.f ? v : expm1f(v), 6.f);
        ((float*)&v4)[j] = v;
    }
    if (hi) ((float4*)(out + (size_t)wid * FOUT))[lane] = v4;
}

// ---------------------------------------------------------------------------
// Workspace layout (77.2 MB):
//   [0, 51.2e6)            xcat bf16 [NN][512]  -- dead after GEMM; overlaid by:
//       [0, 25.6e6)          hn16 f16 [NN][256]
//       [25.6e6, 26.0e6)     sd_s fp32 [NN][2]
//       [26.0e6, 26.4e6)     sd_d fp32 [NN][2]
//   [51.2e6, 76.8e6)       h16  f16 [NN][256]
//   [76.8e6, ~77.2e6)      WcatT bf16 [256][768]
// ---------------------------------------------------------------------------
extern "C" void kernel_launch(void* const* d_in, const int* in_sizes, int n_in,
                              void* d_out, int out_size, void* d_ws, size_t ws_size,
                              hipStream_t stream)
{
    const float* x      = (const float*)d_in[0];
    const int*   edge   = (const int*)d_in[1];
    const float* Wh     = (const float*)d_in[2];
    const float* Wl     = (const float*)d_in[3];
    const float* a_high = (const float*)d_in[4];
    const float* a_low  = (const float*)d_in[5];
    const int*   dstv   = edge + EE;

    char* ws = (char*)d_ws;
    bf16*  xcat  = (bf16*)ws;
    f16*   hn16  = (f16*)ws;                       // alias (after GEMM)
    float* sd_s  = (float*)(ws + 25600000);
    float* sd_d  = (float*)(ws + 26000000);
    f16*   h16   = (f16*)(ws + 51200000);
    bf16*  WcatT = (bf16*)(ws + 76800000);

    split_x_kernel<<<dim3(2048), dim3(256), 0, stream>>>(x, xcat);
    split_w_kernel<<<dim3(256), dim3(256), 0, stream>>>(Wh, Wl, WcatT);
    gemm_mfma_kernel<<<dim3((NN + BM - 1) / BM), dim3(256), 0, stream>>>(xcat, WcatT, h16);
    hn_kernel<<<dim3((NN + 3) / 4), dim3(256), 0, stream>>>(h16, dstv, a_high, a_low,
                                                            hn16, sd_s, sd_d);
    out_kernel<<<dim3((NN + 3) / 4), dim3(256), 0, stream>>>(hn16, dstv, sd_s, sd_d,
                                                             (float*)d_out);
}

// Round 4
// 180.355 us; speedup vs baseline: 2.1253x; 1.0815x over previous
//
#include <hip/hip_runtime.h>
#include <hip/hip_bf16.h>
#include <math.h>

#define NN    50000
#define DEG   16
#define FIN   256
#define FOUT  128
#define EE    (NN * DEG)
#define ALPHA 0.2f

#define BM 64
#define BN 256
#define BK 32
#define KV 768   // virtual K: [xh|xl|xh] x [Wa;Wa;Wb]

typedef __hip_bfloat16 bf16;
typedef _Float16 f16;
typedef __attribute__((ext_vector_type(4))) _Float16 f16x4;
typedef __attribute__((ext_vector_type(8))) short short8;
typedef __attribute__((ext_vector_type(4))) float f32x4;

// ---------------------------------------------------------------------------
// Split x (fp32 [NN][256]) into xcat (bf16 [NN][512] = [xh | xl]).
// ---------------------------------------------------------------------------
__global__ __launch_bounds__(256) void split_x_kernel(
    const float* __restrict__ x, bf16* __restrict__ xcat)
{
    const int total = NN * FIN / 4;
    for (int idx = blockIdx.x * 256 + threadIdx.x; idx < total; idx += gridDim.x * 256) {
        const float4 v = ((const float4*)x)[idx];
        const int row = idx >> 6;
        const int c4  = (idx & 63) * 4;
        short4 sh, sl;
        const float f[4] = {v.x, v.y, v.z, v.w};
#pragma unroll
        for (int j = 0; j < 4; ++j) {
            const bf16 hi = __float2bfloat16(f[j]);
            const bf16 lo = __float2bfloat16(f[j] - __bfloat162float(hi));
            ((bf16*)&sh)[j] = hi;
            ((bf16*)&sl)[j] = lo;
        }
        *(short4*)&xcat[(size_t)row * 512 + c4]       = sh;
        *(short4*)&xcat[(size_t)row * 512 + 256 + c4] = sl;
    }
}

// ---------------------------------------------------------------------------
// Build WcatT bf16 [256][768]: [Wa | Wa | Wb] per n-row.
// ---------------------------------------------------------------------------
__global__ __launch_bounds__(256) void split_w_kernel(
    const float* __restrict__ Wh, const float* __restrict__ Wl,
    bf16* __restrict__ WcatT)
{
    const int k = blockIdx.x;
    const int n = threadIdx.x;
    const float w = (n < FOUT) ? Wh[(size_t)k * FOUT + n]
                               : Wl[(size_t)k * FOUT + (n - FOUT)];
    const bf16 hi = __float2bfloat16(w);
    const bf16 lo = __float2bfloat16(w - __bfloat162float(hi));
    WcatT[(size_t)n * KV + k]       = hi;
    WcatT[(size_t)n * KV + 256 + k] = hi;
    WcatT[(size_t)n * KV + 512 + k] = lo;
}

// ---------------------------------------------------------------------------
// MFMA GEMM: h16[50000][256] = A'(50000x768) @ B'(768x256), fp16 output.
// ---------------------------------------------------------------------------
__global__ __launch_bounds__(256) void gemm_mfma_kernel(
    const bf16* __restrict__ xcat, const bf16* __restrict__ WcatT,
    f16* __restrict__ h16)
{
    __shared__ bf16 As[BM * BK];
    __shared__ bf16 Bs[BN * BK];

    const int t    = threadIdx.x;
    const int lane = t & 63;
    const int w    = t >> 6;
    const int r0   = blockIdx.x * BM;

    f32x4 acc[4][4] = {};

    const int arow = t >> 2;
    const int asl  = ((t & 3) - (arow >> 1)) & 3;
    const size_t abase = (size_t)min(r0 + arow, NN - 1) * 512 + asl * 8;

    int bro[4], bsl[4];
#pragma unroll
    for (int i = 0; i < 4; ++i) {
        const int idx = t + i * 256;
        bro[i] = idx >> 2;
        bsl[i] = ((idx & 3) - (bro[i] >> 1)) & 3;
    }

    const int lr = lane & 15, lg = lane >> 4;

    for (int s = 0; s < KV / BK; ++s) {
        const int kt = s * BK;
        const int kA = (kt < 512) ? kt : kt - 512;

        __builtin_amdgcn_global_load_lds(
            (const __attribute__((address_space(1))) void*)(xcat + abase + kA),
            (__attribute__((address_space(3))) void*)((char*)As + t * 16),
            16, 0, 0);
#pragma unroll
        for (int i = 0; i < 4; ++i) {
            __builtin_amdgcn_global_load_lds(
                (const __attribute__((address_space(1))) void*)
                    (WcatT + (size_t)bro[i] * KV + kt + bsl[i] * 8),
                (__attribute__((address_space(3))) void*)((char*)Bs + (t + i * 256) * 16),
                16, 0, 0);
        }

        __syncthreads();

        short8 af[4], bfr[4];
#pragma unroll
        for (int mi = 0; mi < 4; ++mi) {
            const int row  = mi * 16 + lr;
            const int slot = (lg + (row >> 1)) & 3;
            af[mi] = *(const short8*)((const char*)As + row * 64 + slot * 16);
        }
#pragma unroll
        for (int ni = 0; ni < 4; ++ni) {
            const int row  = w * 64 + ni * 16 + lr;
            const int slot = (lg + (row >> 1)) & 3;
            bfr[ni] = *(const short8*)((const char*)Bs + row * 64 + slot * 16);
        }
#pragma unroll
        for (int mi = 0; mi < 4; ++mi)
#pragma unroll
            for (int ni = 0; ni < 4; ++ni)
                acc[mi][ni] = __builtin_amdgcn_mfma_f32_16x16x32_bf16(
                    af[mi], bfr[ni], acc[mi][ni], 0, 0, 0);

        __syncthreads();
    }

#pragma unroll
    for (int mi = 0; mi < 4; ++mi) {
        const int rowb = r0 + mi * 16 + lg * 4;
#pragma unroll
        for (int r = 0; r < 4; ++r) {
            const int row = rowb + r;
            if (row >= NN) continue;
#pragma unroll
            for (int ni = 0; ni < 4; ++ni)
                h16[(size_t)row * 256 + w * 64 + ni * 16 + lr] = (f16)acc[mi][ni][r];
        }
    }
}

// ---------------------------------------------------------------------------
// Phase B: hn[i] = [16*h_hi[i] + sum_d h_hi[d] | 16*h_lo[i] - sum_d h_lo[d]]
// (fp16 gather table) + per-node logit scalars.
// One wave per node; lane L holds cols [4L, 4L+4): L<32 = hi, L>=32 = lo.
// ---------------------------------------------------------------------------
__global__ __launch_bounds__(256) void hn_kernel(
    const f16* __restrict__ h16, const int* __restrict__ dst,
    const float* __restrict__ a_high, const float* __restrict__ a_low,
    f16* __restrict__ hn16, float* __restrict__ sd_s, float* __restrict__ sd_d)
{
    const int wid  = (blockIdx.x * 256 + threadIdx.x) >> 6;
    const int lane = threadIdx.x & 63;
    if (wid >= NN) return;

    const f16x4 own4 = ((const f16x4*)(h16 + (size_t)wid * 256))[lane];
    float own[4], acc[4];
#pragma unroll
    for (int j = 0; j < 4; ++j) { own[j] = (float)own4[j]; acc[j] = 16.f * own[j]; }

    const float sgn = (lane < 32) ? 1.f : -1.f;
    const int* de = dst + (size_t)wid * DEG;
#pragma unroll
    for (int e = 0; e < DEG; ++e) {
        const f16x4 g = ((const f16x4*)(h16 + (size_t)de[e] * 256))[lane];
#pragma unroll
        for (int j = 0; j < 4; ++j) acc[j] += sgn * (float)g[j];
    }
    f16x4 o;
#pragma unroll
    for (int j = 0; j < 4; ++j) o[j] = (f16)acc[j];
    ((f16x4*)(hn16 + (size_t)wid * 256))[lane] = o;

    // logit scalars: lanes<32 -> (s_hi,d_hi) with a_high; lanes>=32 -> a_low
    const float* av = (lane < 32) ? a_high : a_low;
    const int c0 = (lane & 31) * 4;
    const float4 a_s = *(const float4*)(av + c0);
    const float4 a_d = *(const float4*)(av + 128 + c0);
    float ps = own[0] * a_s.x + own[1] * a_s.y + own[2] * a_s.z + own[3] * a_s.w;
    float pd = own[0] * a_d.x + own[1] * a_d.y + own[2] * a_d.z + own[3] * a_d.w;
#pragma unroll
    for (int off = 16; off > 0; off >>= 1) {
        ps += __shfl_xor(ps, off);
        pd += __shfl_xor(pd, off);
    }
    if ((lane & 31) == 0) {
        sd_s[wid * 2 + (lane >> 5)] = ps;   // [0]=s_hi, [1]=s_lo
        sd_d[wid * 2 + (lane >> 5)] = pd;   // [0]=d_hi, [1]=d_lo
    }
}

// ---------------------------------------------------------------------------
// Phase C (v2, wave-parallel weights): lane e (0..15) computes edge e's hi
// weight, lane 16+e the lo weight (lanes 32..63 mirror, harmless); 16-lane
// butterfly gives rowsums; gather loop pulls w/d via __shfl.
// rowsum uses UNCLIPPED e; numerator uses min(e,6) — matches reference.
// ---------------------------------------------------------------------------
__global__ __launch_bounds__(256) void out_kernel(
    const f16* __restrict__ hn16, const int* __restrict__ dst,
    const float* __restrict__ sd_s, const float* __restrict__ sd_d,
    float* __restrict__ out)
{
    const int wid  = (blockIdx.x * 256 + threadIdx.x) >> 6;
    const int lane = threadIdx.x & 63;
    if (wid >= NN) return;

    const int* de   = dst + (size_t)wid * DEG;
    const int  d_my = de[lane & 15];

    // per-lane logit + exp (hi for lanes 0-15/32-47, lo for 16-31/48-63)
    const bool whi = (lane & 16) == 0;
    const float2 s2 = ((const float2*)sd_s)[wid];
    const float2 dd = ((const float2*)sd_d)[d_my];
    const float l   = whi ? (s2.x + dd.x) : (s2.y + dd.y);
    const float ev  = __expf(-(l >= 0.f ? l : ALPHA * l));

    // rowsum over the 16-lane group (unclipped e)
    float rs = ev;
    rs += __shfl_xor(rs, 1);
    rs += __shfl_xor(rs, 2);
    rs += __shfl_xor(rs, 4);
    rs += __shfl_xor(rs, 8);
    const float wgt = fminf(ev, 6.f);

    // accumulation channel: lanes 0-31 = hi cols, 32-63 = lo cols
    const bool chi  = (lane < 32);
    const int  wsrc = chi ? 0 : 16;
    const float inv = 1.f / (__shfl(rs, wsrc) + 1e-16f);

    float acc[4] = {0.f, 0.f, 0.f, 0.f};
#pragma unroll
    for (int e = 0; e < DEG; ++e) {
        const int   d = __shfl(d_my, e);
        const float w = __shfl(wgt, wsrc + e);
        const f16x4 g = ((const f16x4*)(hn16 + (size_t)d * 256))[lane];
#pragma unroll
        for (int j = 0; j < 4; ++j) acc[j] += w * (float)g[j];
    }

    float4 v4;
#pragma unroll
    for (int j = 0; j < 4; ++j) {
        const float val   = acc[j] * inv;
        const float other = __shfl_xor(val, 32);
        float v = 0.5f * (val + other);
        v = fminf(v > 0.f ? v : expm1f(v), 6.f);
        ((float*)&v4)[j] = v;
    }
    if (chi) ((float4*)(out + (size_t)wid * FOUT))[lane] = v4;
}

// ---------------------------------------------------------------------------
// Workspace layout (77.2 MB):
//   [0, 51.2e6)            xcat bf16 [NN][512]  -- dead after GEMM; overlaid by:
//       [0, 25.6e6)          hn16 f16 [NN][256]
//       [25.6e6, 26.0e6)     sd_s fp32 [NN][2]
//       [26.0e6, 26.4e6)     sd_d fp32 [NN][2]
//   [51.2e6, 76.8e6)       h16  f16 [NN][256]
//   [76.8e6, ~77.2e6)      WcatT bf16 [256][768]
// ---------------------------------------------------------------------------
extern "C" void kernel_launch(void* const* d_in, const int* in_sizes, int n_in,
                              void* d_out, int out_size, void* d_ws, size_t ws_size,
                              hipStream_t stream)
{
    const float* x      = (const float*)d_in[0];
    const int*   edge   = (const int*)d_in[1];
    const float* Wh     = (const float*)d_in[2];
    const float* Wl     = (const float*)d_in[3];
    const float* a_high = (const float*)d_in[4];
    const float* a_low  = (const float*)d_in[5];
    const int*   dstv   = edge + EE;

    char* ws = (char*)d_ws;
    bf16*  xcat  = (bf16*)ws;
    f16*   hn16  = (f16*)ws;                       // alias (after GEMM)
    float* sd_s  = (float*)(ws + 25600000);
    float* sd_d  = (float*)(ws + 26000000);
    f16*   h16   = (f16*)(ws + 51200000);
    bf16*  WcatT = (bf16*)(ws + 76800000);

    split_x_kernel<<<dim3(2048), dim3(256), 0, stream>>>(x, xcat);
    split_w_kernel<<<dim3(256), dim3(256), 0, stream>>>(Wh, Wl, WcatT);
    gemm_mfma_kernel<<<dim3((NN + BM - 1) / BM), dim3(256), 0, stream>>>(xcat, WcatT, h16);
    hn_kernel<<<dim3((NN + 3) / 4), dim3(256), 0, stream>>>(h16, dstv, a_high, a_low,
                                                            hn16, sd_s, sd_d);
    out_kernel<<<dim3((NN + 3) / 4), dim3(256), 0, stream>>>(hn16, dstv, sd_s, sd_d,
                                                             (float*)d_out);
}